// Round 6
// baseline (156.854 us; speedup 1.0000x reference)
//
#include <hip/hip_runtime.h>

#define HQ 32
#define HKV 8
#define DH 128
#define WIN 256
#define META 128
#define QSCALE 0.1275174324f    // rsqrt(128) * log2(e)  (scores produced in log2 space)
#define NFREQ 0.20762050594046f // log2(10000)/64: invfreq(i) = exp2(-NFREQ*i)

typedef __attribute__((ext_vector_type(8))) __bf16 bf16x8;
typedef __attribute__((ext_vector_type(16))) float f32x16;
typedef __attribute__((ext_vector_type(4))) unsigned int u32x4;
typedef unsigned short u16;
typedef unsigned int u32;

__device__ __forceinline__ u16 f2bf(float f) {
  u32 u = __float_as_uint(f);
  u += 0x7FFFu + ((u >> 16) & 1u);
  return (u16)(u >> 16);
}
__device__ __forceinline__ u32 packbf(float a, float b) {  // a->lo16, b->hi16
  u32 ua = __float_as_uint(a); ua += 0x7FFFu + ((ua >> 16) & 1u);
  u32 ub = __float_as_uint(b); ub += 0x7FFFu + ((ub >> 16) & 1u);
  return (ua >> 16) | (ub & 0xFFFF0000u);
}

// ---------- prep: RoPE(K) -> Kr[hk][s][d] bf16 ; V -> Vt[hk][d][s] bf16 ----------
__global__ __launch_bounds__(256)
void prep_kv(const float* __restrict__ Kg, const float* __restrict__ Vg,
             u16* __restrict__ Kr, u16* __restrict__ Vt, int S) {
  __shared__ float T[64][132];
  const int hk = blockIdx.x;
  const int s0 = blockIdx.y * 64;
  const int tid = threadIdx.x;
  // K rope: 4 threads/row, 16 pairs each
  {
    const int r = tid >> 2, c0 = (tid & 3) * 16;
    const int s = s0 + r;
    const float pos = (float)s;
    const float* src = Kg + ((size_t)s * HKV + hk) * DH;
    u16* dst = Kr + ((size_t)hk * S + s) * DH;
    float x[16], y[16];
    #pragma unroll
    for (int j = 0; j < 16; j += 4) {
      *(float4*)&x[j] = *(const float4*)(src + c0 + j);
      *(float4*)&y[j] = *(const float4*)(src + c0 + 64 + j);
    }
    u16 lo[16], hb[16];
    #pragma unroll
    for (int j = 0; j < 16; ++j) {
      float iv = __builtin_amdgcn_exp2f(-NFREQ * (float)(c0 + j));
      float sv, cv; __sincosf(pos * iv, &sv, &cv);
      lo[j] = f2bf(x[j] * cv - y[j] * sv);
      hb[j] = f2bf(y[j] * cv + x[j] * sv);
    }
    *(int4*)(dst + c0)      = *(int4*)&lo[0];
    *(int4*)(dst + c0 + 8)  = *(int4*)&lo[8];
    *(int4*)(dst + c0 + 64) = *(int4*)&hb[0];
    *(int4*)(dst + c0 + 72) = *(int4*)&hb[8];
  }
  // V transpose: stage fp32, write d-major bf16
  {
    const int r = tid >> 2, c = (tid & 3) * 32;
    const float* src = Vg + ((size_t)(s0 + r) * HKV + hk) * DH + c;
    #pragma unroll
    for (int j = 0; j < 32; j += 4) *(float4*)&T[r][c + j] = *(const float4*)(src + j);
  }
  __syncthreads();
  {
    const int d = tid >> 1, hf = (tid & 1) * 32;
    u16 buf[32];
    #pragma unroll
    for (int i = 0; i < 32; ++i) buf[i] = f2bf(T[hf + i][d]);
    u16* dst = Vt + ((size_t)hk * DH + d) * S + s0 + hf;
    #pragma unroll
    for (int j = 0; j < 4; ++j) *(int4*)(dst + j * 8) = *(int4*)&buf[j * 8];
  }
}

// ---------- main: one wave per 32 q rows. No LDS, no barriers. ----------
// Frags load straight from global (L2-resident Kr/Vt); Q RoPE is in-register
// (pairs (c,c+64) are lane-local in the B-frag layout). Head swizzle puts one
// kv-head per XCD-L2 (block->XCD ~ lin%8, and lin%8 == blockIdx.x%8 here).
__global__ __launch_bounds__(64, 2)
void attn_main(const float* __restrict__ Qg, const u16* __restrict__ Kr,
               const u16* __restrict__ Vt, float* __restrict__ Og, int S) {
  const int bx = blockIdx.x;
  const int h  = ((bx & 7) << 2) | (bx >> 3);   // hk == bx % 8
  const int hk = bx & 7;
  const int qi = (int)gridDim.y - 1 - (int)blockIdx.y;  // heavy q-tiles first
  const int qw0 = qi * 32;
  const int lane = threadIdx.x;
  const int ln31 = lane & 31;
  const int hi = lane >> 5;
  const int kh = hi * 8;
  const int q = qw0 + ln31;          // this lane's q row (S^T col)

  // ---- Q: global fp32 -> in-register RoPE*QSCALE -> bf16 B-frags ----
  bf16x8 qa[8];                      // qa[kk][j] = Q'[q][kh + 16*kk + j]
  {
    const float* qrow = Qg + ((size_t)q * HQ + h) * DH;
    const float pos = (float)q;
    #pragma unroll
    for (int kk = 0; kk < 4; ++kk) {
      float x[8], y[8];
      *(float4*)&x[0] = *(const float4*)(qrow + kh + 16 * kk);
      *(float4*)&x[4] = *(const float4*)(qrow + kh + 16 * kk + 4);
      *(float4*)&y[0] = *(const float4*)(qrow + kh + 16 * kk + 64);
      *(float4*)&y[4] = *(const float4*)(qrow + kh + 16 * kk + 68);
      float lof[8], hbf[8];
      #pragma unroll
      for (int j = 0; j < 8; ++j) {
        const int c = kh + 16 * kk + j;
        float iv = __builtin_amdgcn_exp2f(-NFREQ * (float)c);
        float sv, cv; __sincosf(pos * iv, &sv, &cv);
        lof[j] = (x[j] * cv - y[j] * sv) * QSCALE;
        hbf[j] = (y[j] * cv + x[j] * sv) * QSCALE;
      }
      u32x4 pl = { packbf(lof[0], lof[1]), packbf(lof[2], lof[3]),
                   packbf(lof[4], lof[5]), packbf(lof[6], lof[7]) };
      u32x4 ph = { packbf(hbf[0], hbf[1]), packbf(hbf[2], hbf[3]),
                   packbf(hbf[4], hbf[5]), packbf(hbf[6], hbf[7]) };
      qa[kk]     = __builtin_bit_cast(bf16x8, pl);   // cols c
      qa[kk + 4] = __builtin_bit_cast(bf16x8, ph);   // cols c+64
    }
  }

  // KV tile schedule: meta tiles {0,64} + window tiles [wstart .. (qw0+31)&~63]
  int wstart = (qw0 - WIN) & ~63; if (wstart < META) wstart = META;
  const int nwin = (qw0 >= META) ? (((qw0 + 31) & ~63) - wstart) / 64 + 1 : 0;
  const int ntiles = 2 + nwin;

  f32x16 acc[4];                     // O^T: acc[dt], rows d = dt*32 + C-pattern, col q
  #pragma unroll
  for (int d = 0; d < 4; ++d)
    #pragma unroll
    for (int r = 0; r < 16; ++r) acc[d][r] = 0.f;
  float m_i = -1e30f, l_i = 0.f;

  const u16* Kbh = Kr + (size_t)hk * S * DH;
  const u16* Vbh = Vt + ((size_t)hk * DH + ln31) * S;   // + dt*32*S rows

  for (int t = 0; t < ntiles; ++t) {
    const int kv0 = (t < 2) ? t * 64 : wstart + (t - 2) * 64;
    if (kv0 > qw0 + 31) continue;    // future tile (small qw0 meta case)

    // ---- K A-frags straight from global: rows kv0+ln31 / kv0+32+ln31 ----
    bf16x8 k0[8], k1[8];
    {
      const u16* kp0 = Kbh + (size_t)(kv0 + ln31) * DH + kh;
      const u16* kp1 = kp0 + 32 * DH;
      #pragma unroll
      for (int kk = 0; kk < 8; ++kk) {
        k0[kk] = *(const bf16x8*)(kp0 + 16 * kk);
        k1[kk] = *(const bf16x8*)(kp1 + 16 * kk);
      }
    }

    // ---- S^T = K Q^T : two 32x32 C-tiles ----
    f32x16 s0v, s1v;
    #pragma unroll
    for (int r = 0; r < 16; ++r) { s0v[r] = 0.f; s1v[r] = 0.f; }
    #pragma unroll
    for (int kk = 0; kk < 8; ++kk) {
      s0v = __builtin_amdgcn_mfma_f32_32x32x16_bf16(k0[kk], qa[kk], s0v, 0, 0, 0);
      s1v = __builtin_amdgcn_mfma_f32_32x32x16_bf16(k1[kk], qa[kk], s1v, 0, 0, 0);
    }

    // ---- mask (in-register) ----
    const bool fullv = (kv0 + 63 <= qw0) &&
                       ((kv0 + 63 < META) || (qw0 + 31 - kv0 <= WIN));
    if (!fullv) {
      #pragma unroll
      for (int r = 0; r < 16; ++r) {
        const int kva = kv0 + (r & 3) + 8 * (r >> 2) + 4 * hi;
        const int kvb = kva + 32;
        if (!((kva <= q) && (((q - kva) <= WIN) || (kva < META)))) s0v[r] = -1e30f;
        if (!((kvb <= q) && (((q - kvb) <= WIN) || (kvb < META)))) s1v[r] = -1e30f;
      }
    }

    // ---- V^T B-operand frags from global (land during softmax VALU) ----
    bf16x8 vf0[4], vf1[4], vf2[4], vf3[4];
    {
      const u16* vp = Vbh + kv0 + kh;
      #pragma unroll
      for (int p = 0; p < 4; ++p) {
        vf0[p] = *(const bf16x8*)(vp + 16 * p);
        vf1[p] = *(const bf16x8*)(vp + 32 * S + 16 * p);
        vf2[p] = *(const bf16x8*)(vp + 64 * S + 16 * p);
        vf3[p] = *(const bf16x8*)(vp + 96 * S + 16 * p);
      }
    }

    // ---- online softmax: register reduction + one cross-half shuffle each ----
    float mx = -1e30f;
    #pragma unroll
    for (int r = 0; r < 16; ++r) mx = fmaxf(mx, fmaxf(s0v[r], s1v[r]));
    mx = fmaxf(mx, __shfl_xor(mx, 32));
    const float mnew = fmaxf(m_i, mx);
    const float al = __builtin_amdgcn_exp2f(m_i - mnew);
    m_i = mnew;
    float ps = 0.f;
    #pragma unroll
    for (int r = 0; r < 16; ++r) {
      s0v[r] = __builtin_amdgcn_exp2f(s0v[r] - mnew);
      s1v[r] = __builtin_amdgcn_exp2f(s1v[r] - mnew);
      ps += s0v[r] + s1v[r];
    }
    ps += __shfl_xor(ps, 32);
    l_i = l_i * al + ps;
    #pragma unroll
    for (int d = 0; d < 4; ++d)
      #pragma unroll
      for (int r = 0; r < 16; ++r) acc[d][r] *= al;

    // ---- P^T: C-layout -> B-operand layout via cross-half shuffles ----
    u32 pk0[8], pk1[8], sh0[8], sh1[8];
    #pragma unroll
    for (int m = 0; m < 8; ++m) {
      pk0[m] = packbf(s0v[2 * m], s0v[2 * m + 1]);
      pk1[m] = packbf(s1v[2 * m], s1v[2 * m + 1]);
    }
    #pragma unroll
    for (int m = 0; m < 8; ++m) {
      sh0[m] = (u32)__shfl_xor((int)pk0[m], 32);
      sh1[m] = (u32)__shfl_xor((int)pk1[m], 32);
    }
    u32x4 bl0 = { hi ? sh0[2] : pk0[0], hi ? sh0[3] : pk0[1],
                  hi ? pk0[2] : sh0[0], hi ? pk0[3] : sh0[1] };
    u32x4 bh0 = { hi ? sh0[6] : pk0[4], hi ? sh0[7] : pk0[5],
                  hi ? pk0[6] : sh0[4], hi ? pk0[7] : sh0[5] };
    u32x4 bl1 = { hi ? sh1[2] : pk1[0], hi ? sh1[3] : pk1[1],
                  hi ? pk1[2] : sh1[0], hi ? pk1[3] : sh1[1] };
    u32x4 bh1 = { hi ? sh1[6] : pk1[4], hi ? sh1[7] : pk1[5],
                  hi ? pk1[6] : sh1[4], hi ? pk1[7] : sh1[5] };
    const bf16x8 pbl0 = __builtin_bit_cast(bf16x8, bl0);
    const bf16x8 pbh0 = __builtin_bit_cast(bf16x8, bh0);
    const bf16x8 pbl1 = __builtin_bit_cast(bf16x8, bl1);
    const bf16x8 pbh1 = __builtin_bit_cast(bf16x8, bh1);

    // ---- O^T += V^T P^T ----
    #pragma unroll
    for (int p = 0; p < 4; ++p) {
      const bf16x8 pb = (p == 0) ? pbl0 : (p == 1) ? pbh0 : (p == 2) ? pbl1 : pbh1;
      acc[0] = __builtin_amdgcn_mfma_f32_32x32x16_bf16(vf0[p], pb, acc[0], 0, 0, 0);
      acc[1] = __builtin_amdgcn_mfma_f32_32x32x16_bf16(vf1[p], pb, acc[1], 0, 0, 0);
      acc[2] = __builtin_amdgcn_mfma_f32_32x32x16_bf16(vf2[p], pb, acc[2], 0, 0, 0);
      acc[3] = __builtin_amdgcn_mfma_f32_32x32x16_bf16(vf3[p], pb, acc[3], 0, 0, 0);
    }
  }

  // ---- epilogue: O^T C-layout -> row-major out, 16B stores ----
  const float inv = 1.0f / l_i;
  float* ob = Og + ((size_t)q * HQ + h) * DH;
  #pragma unroll
  for (int dt = 0; dt < 4; ++dt) {
    #pragma unroll
    for (int g = 0; g < 4; ++g) {     // d = dt*32 + 8*g + 4*hi + {0..3}
      float4 o = { acc[dt][4 * g + 0] * inv, acc[dt][4 * g + 1] * inv,
                   acc[dt][4 * g + 2] * inv, acc[dt][4 * g + 3] * inv };
      *(float4*)(ob + dt * 32 + 8 * g + 4 * hi) = o;
    }
  }
}

extern "C" void kernel_launch(void* const* d_in, const int* in_sizes, int n_in,
                              void* d_out, int out_size, void* d_ws, size_t ws_size,
                              hipStream_t stream) {
  const float* Qg = (const float*)d_in[0];
  const float* Kg = (const float*)d_in[1];
  const float* Vg = (const float*)d_in[2];
  float* Og = (float*)d_out;
  const int S = in_sizes[0] / (HQ * DH);   // 2176

  u16* Kr = (u16*)d_ws;                                     // 8*S*128 bf16 = 4.45 MB
  u16* Vt = (u16*)((char*)d_ws + (size_t)HKV * S * DH * 2); // 4.45 MB

  prep_kv<<<dim3(HKV, S / 64), dim3(256), 0, stream>>>(Kg, Vg, Kr, Vt, S);
  attn_main<<<dim3(HQ, S / 32), dim3(64), 0, stream>>>(Qg, Kr, Vt, Og, S);
}